// Round 1
// baseline (12167.863 us; speedup 1.0000x reference)
//
#include <hip/hip_runtime.h>
#include <cstdint>
#include <cstddef>

#define NP  160000   // total points (B*T)
#define NB  8        // batch
#define TPB 20000    // points per batch
#define H   128      // hidden dim
#define SS  4096     // bins per plane (64*64)

// order-preserving float <-> u32 map for atomicMax-based scatter-max
__device__ __forceinline__ unsigned encf(float f) {
  unsigned u = __float_as_uint(f);
  return (u & 0x80000000u) ? ~u : (u | 0x80000000u);
}
__device__ __forceinline__ float decf(unsigned u) {
  unsigned b = (u & 0x80000000u) ? (u ^ 0x80000000u) : ~u;
  return __uint_as_float(b);
}

// ---------------- bin indices + counts ----------------
__global__ __launch_bounds__(256) void k_idx(const float* __restrict__ p,
                                             int* __restrict__ idx,
                                             unsigned* __restrict__ cnt) {
  int n = blockIdx.x * 256 + threadIdx.x;
  if (n >= NP) return;
  const float DEN = (float)(1.0 + 0.1 + 1e-3);   // 1.101, matches reference
  const float HI  = (float)(1.0 - 1e-3);
  float px = p[3*n], py = p[3*n+1], pz = p[3*n+2];
  float nx = fminf(fmaxf(px / DEN + 0.5f, 0.0f), HI);
  float ny = fminf(fmaxf(py / DEN + 0.5f, 0.0f), HI);
  float nz = fminf(fmaxf(pz / DEN + 0.5f, 0.0f), HI);
  int ix = (int)(nx * 64.0f);
  int iy = (int)(ny * 64.0f);
  int iz = (int)(nz * 64.0f);
  int b = n / TPB;
  int i0 = ix + 64 * iz;   // plane (0,2) xz
  int i1 = ix + 64 * iy;   // plane (0,1) xy
  int i2 = iy + 64 * iz;   // plane (1,2) yz
  idx[0*NP + n] = i0;
  idx[1*NP + n] = i1;
  idx[2*NP + n] = i2;
  atomicAdd(&cnt[(0*NB + b)*SS + i0], 1u);
  atomicAdd(&cnt[(1*NB + b)*SS + i1], 1u);
  atomicAdd(&cnt[(2*NB + b)*SS + i2], 1u);
}

// ---------------- scatter-max (3 planes) ----------------
__global__ __launch_bounds__(256) void k_scatter(const float* __restrict__ net,
                                                 const int* __restrict__ idx,
                                                 unsigned* __restrict__ ubuf) {
  int i = blockIdx.x * 256 + threadIdx.x;     // NP*32 threads
  int n = i >> 5;
  int f4 = (i & 31) << 2;
  int b = n / TPB;
  float4 v = *(const float4*)&net[(size_t)n*H + f4];
  unsigned e0 = encf(v.x), e1 = encf(v.y), e2 = encf(v.z), e3 = encf(v.w);
  #pragma unroll
  for (int pl = 0; pl < 3; ++pl) {
    int bin = idx[pl*NP + n];
    unsigned* u = &ubuf[(((size_t)(pl*NB + b))*SS + bin)*H + f4];
    atomicMax(u + 0, e0);
    atomicMax(u + 1, e1);
    atomicMax(u + 2, e2);
    atomicMax(u + 3, e3);
  }
}

// ---------------- fused ResnetBlockFC ----------------
// MODE 0: x = fc_pos(p) (256 wide), computed into LDS during staging.
// MODE 1: x = concat(net, sum_planes gather(scatter_max buf)).
// Block: 64 points, 256 threads. Thread tile: 8 points x 4 features.
template<int MODE>
__global__ __launch_bounds__(256) void k_block(
    const float* __restrict__ p,
    const float* __restrict__ wpos, const float* __restrict__ bpos,
    float* __restrict__ net,
    const unsigned* __restrict__ ubuf, const int* __restrict__ idx,
    const float* __restrict__ w0, const float* __restrict__ b0,
    const float* __restrict__ w1, const float* __restrict__ b1,
    const float* __restrict__ wsc)
{
  __shared__ float xa[64][H];   // x[0:128]
  __shared__ float xb[64][H];   // x[128:256]
  const int tid = threadIdx.x;
  const int n0 = blockIdx.x * 64;

  if (MODE == 0) {
    for (int j = tid; j < 64 * 64; j += 256) {
      const int pt = j >> 6;
      const int k4 = (j & 63) << 2;
      const int n = n0 + pt;
      const float px = p[3*n], py = p[3*n+1], pz = p[3*n+2];
      float4 a = *(const float4*)&bpos[k4];
      const float4 wx = *(const float4*)&wpos[k4];
      const float4 wy = *(const float4*)&wpos[256 + k4];
      const float4 wz = *(const float4*)&wpos[512 + k4];
      a.x += px*wx.x + py*wy.x + pz*wz.x;
      a.y += px*wx.y + py*wy.y + pz*wz.y;
      a.z += px*wx.z + py*wy.z + pz*wz.z;
      a.w += px*wx.w + py*wy.w + pz*wz.w;
      if (k4 < H) *(float4*)&xa[pt][k4] = a;
      else        *(float4*)&xb[pt][k4 - H] = a;
    }
  } else {
    for (int j = tid; j < 64 * 32; j += 256) {
      const int pt = j >> 5;
      const int k4 = (j & 31) << 2;
      const int n = n0 + pt;
      *(float4*)&xa[pt][k4] = *(const float4*)&net[(size_t)n*H + k4];
      const int b = n / TPB;
      float4 s = make_float4(0.f, 0.f, 0.f, 0.f);
      #pragma unroll
      for (int pl = 0; pl < 3; ++pl) {
        const int bin = idx[pl*NP + n];
        const uint4 u = *(const uint4*)&ubuf[(((size_t)(pl*NB + b))*SS + bin)*H + k4];
        s.x += decf(u.x); s.y += decf(u.y); s.z += decf(u.z); s.w += decf(u.w);
      }
      *(float4*)&xb[pt][k4] = s;
    }
  }
  __syncthreads();

  const int fg = tid & 31;
  const int pg = tid >> 5;
  const int f4 = fg << 2;
  const int prow = pg << 3;

  float a0[8][4];
  float as[8][4];
  #pragma unroll
  for (int i = 0; i < 8; ++i) {
    a0[i][0]=a0[i][1]=a0[i][2]=a0[i][3]=0.f;
    as[i][0]=as[i][1]=as[i][2]=as[i][3]=0.f;
  }

  // phase A part 1: k = 0..127 over xa (fc_0 on relu(x), shortcut on raw x)
  #pragma unroll 4
  for (int k = 0; k < H; ++k) {
    const float4 w0v = *(const float4*)&w0[(size_t)k*H + f4];
    const float4 wsv = *(const float4*)&wsc[(size_t)k*H + f4];
    #pragma unroll
    for (int i = 0; i < 8; ++i) {
      const float xv = xa[prow + i][k];
      const float r = fmaxf(xv, 0.f);
      a0[i][0] += r*w0v.x; a0[i][1] += r*w0v.y; a0[i][2] += r*w0v.z; a0[i][3] += r*w0v.w;
      as[i][0] += xv*wsv.x; as[i][1] += xv*wsv.y; as[i][2] += xv*wsv.z; as[i][3] += xv*wsv.w;
    }
  }
  // phase A part 2: k = 128..255 over xb
  #pragma unroll 4
  for (int k = 0; k < H; ++k) {
    const float4 w0v = *(const float4*)&w0[(size_t)(k + H)*H + f4];
    const float4 wsv = *(const float4*)&wsc[(size_t)(k + H)*H + f4];
    #pragma unroll
    for (int i = 0; i < 8; ++i) {
      const float xv = xb[prow + i][k];
      const float r = fmaxf(xv, 0.f);
      a0[i][0] += r*w0v.x; a0[i][1] += r*w0v.y; a0[i][2] += r*w0v.z; a0[i][3] += r*w0v.w;
      as[i][0] += xv*wsv.x; as[i][1] += xv*wsv.y; as[i][2] += xv*wsv.z; as[i][3] += xv*wsv.w;
    }
  }
  __syncthreads();

  // h = relu(fc0 + b0) -> reuse xa
  const float4 b0v = *(const float4*)&b0[f4];
  #pragma unroll
  for (int i = 0; i < 8; ++i) {
    float4 h;
    h.x = fmaxf(a0[i][0] + b0v.x, 0.f);
    h.y = fmaxf(a0[i][1] + b0v.y, 0.f);
    h.z = fmaxf(a0[i][2] + b0v.z, 0.f);
    h.w = fmaxf(a0[i][3] + b0v.w, 0.f);
    *(float4*)&xa[prow + i][f4] = h;
  }
  __syncthreads();

  // phase B: dx = h @ w1, accumulate into shortcut
  #pragma unroll 4
  for (int k = 0; k < H; ++k) {
    const float4 w1v = *(const float4*)&w1[(size_t)k*H + f4];
    #pragma unroll
    for (int i = 0; i < 8; ++i) {
      const float hv = xa[prow + i][k];
      as[i][0] += hv*w1v.x; as[i][1] += hv*w1v.y; as[i][2] += hv*w1v.z; as[i][3] += hv*w1v.w;
    }
  }

  const float4 b1v = *(const float4*)&b1[f4];
  #pragma unroll
  for (int i = 0; i < 8; ++i) {
    float4 o;
    o.x = as[i][0] + b1v.x;
    o.y = as[i][1] + b1v.y;
    o.z = as[i][2] + b1v.z;
    o.w = as[i][3] + b1v.w;
    *(float4*)&net[(size_t)(n0 + prow + i)*H + f4] = o;
  }
}

// ---------------- fc_c + scatter-mean sums ----------------
__global__ __launch_bounds__(256) void k_final(const float* __restrict__ net,
                                               const int* __restrict__ idx,
                                               const float* __restrict__ wc,
                                               const float* __restrict__ bc,
                                               float* __restrict__ sums) {
  __shared__ float xa[64][H];
  const int tid = threadIdx.x;
  const int n0 = blockIdx.x * 64;
  for (int j = tid; j < 64 * 32; j += 256) {
    const int pt = j >> 5;
    const int k4 = (j & 31) << 2;
    *(float4*)&xa[pt][k4] = *(const float4*)&net[(size_t)(n0 + pt)*H + k4];
  }
  __syncthreads();

  const int fg = tid & 31;
  const int pg = tid >> 5;
  const int f4 = fg << 2;
  const int prow = pg << 3;

  float ac[8][4];
  #pragma unroll
  for (int i = 0; i < 8; ++i) { ac[i][0]=ac[i][1]=ac[i][2]=ac[i][3]=0.f; }

  #pragma unroll 4
  for (int k = 0; k < H; ++k) {
    const float4 wv = *(const float4*)&wc[(size_t)k*H + f4];
    #pragma unroll
    for (int i = 0; i < 8; ++i) {
      const float xv = xa[prow + i][k];
      ac[i][0] += xv*wv.x; ac[i][1] += xv*wv.y; ac[i][2] += xv*wv.z; ac[i][3] += xv*wv.w;
    }
  }

  const float4 bv = *(const float4*)&bc[f4];
  #pragma unroll
  for (int i = 0; i < 8; ++i) {
    const int n = n0 + prow + i;
    const int b = n / TPB;
    const float c0 = ac[i][0] + bv.x;
    const float c1 = ac[i][1] + bv.y;
    const float c2 = ac[i][2] + bv.z;
    const float c3 = ac[i][3] + bv.w;
    #pragma unroll
    for (int pl = 0; pl < 3; ++pl) {
      const int bin = idx[pl*NP + n];
      float* s = &sums[(((size_t)(pl*NB + b))*SS + bin)*H + f4];
      atomicAdd(s + 0, c0);
      atomicAdd(s + 1, c1);
      atomicAdd(s + 2, c2);
      atomicAdd(s + 3, c3);
    }
  }
}

// ---------------- normalize + transpose to [3,B,C,64,64] ----------------
__global__ __launch_bounds__(256) void k_out(const float* __restrict__ sums,
                                             const unsigned* __restrict__ cnt,
                                             float* __restrict__ out) {
  const int bid = blockIdx.x;          // 24 * 64 blocks
  const int plb = bid >> 6;            // 0..23  (pl*8 + b)
  const int s0 = (bid & 63) << 6;      // tile of 64 s-values
  __shared__ float t[64][129];
  const int tid = threadIdx.x;

  for (int j = tid; j < 64 * 32; j += 256) {
    const int si = j >> 5;
    const int k4 = (j & 31) << 2;
    const int s = s0 + si;
    const float4 v = *(const float4*)&sums[((size_t)plb*SS + s)*H + k4];
    const unsigned c = cnt[(size_t)plb*SS + s];
    const float r = 1.0f / (float)(c > 0u ? c : 1u);
    t[si][k4 + 0] = v.x * r;
    t[si][k4 + 1] = v.y * r;
    t[si][k4 + 2] = v.z * r;
    t[si][k4 + 3] = v.w * r;
  }
  __syncthreads();

  for (int j = tid; j < H * 16; j += 256) {
    const int ch = j >> 4;
    const int s4 = (j & 15) << 2;
    float4 o;
    o.x = t[s4 + 0][ch];
    o.y = t[s4 + 1][ch];
    o.z = t[s4 + 2][ch];
    o.w = t[s4 + 3][ch];
    *(float4*)&out[((size_t)plb*H + ch)*SS + s0 + s4] = o;
  }
}

extern "C" void kernel_launch(void* const* d_in, const int* in_sizes, int n_in,
                              void* d_out, int out_size, void* d_ws, size_t ws_size,
                              hipStream_t stream) {
  (void)in_sizes; (void)n_in; (void)out_size; (void)ws_size;
  const float* p      = (const float*)d_in[0];
  const float* wpos   = (const float*)d_in[1];
  const float* bpos   = (const float*)d_in[2];
  const float* blk0w  = (const float*)d_in[3];
  const float* blk0b  = (const float*)d_in[4];
  const float* blk1w  = (const float*)d_in[5];
  const float* blk1b  = (const float*)d_in[6];
  const float* blkscw = (const float*)d_in[7];
  const float* wc     = (const float*)d_in[8];
  const float* bc     = (const float*)d_in[9];
  float* out = (float*)d_out;

  char* ws = (char*)d_ws;
  int* idx       = (int*)ws;                              // 3*NP*4        = 1,920,000 B
  unsigned* cnt  = (unsigned*)(ws + 1920000);             // 3*NB*SS*4     =   393,216 B
  unsigned* ubuf = (unsigned*)(ws + 2313216);             // 3*NB*SS*H*4   = 50,331,648 B
  float* net     = (float*)(ws + 52644864);               // NP*H*4        = 81,920,000 B

  const size_t ubuf_bytes = (size_t)3 * NB * SS * H * 4;

  hipMemsetAsync(cnt, 0, (size_t)3 * NB * SS * 4, stream);
  k_idx<<<(NP + 255) / 256, 256, 0, stream>>>(p, idx, cnt);

  // block 0: fc_pos fused
  k_block<0><<<NP / 64, 256, 0, stream>>>(p, wpos, bpos, net, nullptr, nullptr,
                                          blk0w, blk0b, blk1w, blk1b, blkscw);

  for (int i = 1; i < 5; ++i) {
    hipMemsetAsync(ubuf, 0, ubuf_bytes, stream);
    k_scatter<<<(NP * 32) / 256, 256, 0, stream>>>(net, idx, ubuf);
    k_block<1><<<NP / 64, 256, 0, stream>>>(nullptr, nullptr, nullptr, net, ubuf, idx,
                                            blk0w + (size_t)i * 256 * H,
                                            blk0b + (size_t)i * H,
                                            blk1w + (size_t)i * H * H,
                                            blk1b + (size_t)i * H,
                                            blkscw + (size_t)i * 256 * H);
  }

  hipMemsetAsync(ubuf, 0, ubuf_bytes, stream);
  k_final<<<NP / 64, 256, 0, stream>>>(net, idx, wc, bc, (float*)ubuf);
  k_out<<<24 * 64, 256, 0, stream>>>((const float*)ubuf, cnt, out);
}

// Round 2
// 3829.298 us; speedup vs baseline: 3.1776x; 3.1776x over previous
//
#include <hip/hip_runtime.h>
#include <cstdint>
#include <cstddef>

#define NP   160000   // total points (B*T)
#define NB   8        // batch
#define TPB  20000    // points per batch
#define H    128      // hidden dim
#define SS   4096     // bins per plane (64*64)
#define OFFP 4097     // off-array pitch per (plane,batch)

__device__ __forceinline__ float4 max4(float4 a, float4 b) {
  return make_float4(fmaxf(a.x,b.x), fmaxf(a.y,b.y), fmaxf(a.z,b.z), fmaxf(a.w,b.w));
}

// ---------------- bin indices + counts ----------------
__global__ __launch_bounds__(256) void k_idx(const float* __restrict__ p,
                                             int* __restrict__ idx,
                                             unsigned* __restrict__ cnt) {
  int n = blockIdx.x * 256 + threadIdx.x;
  if (n >= NP) return;
  const float DEN = (float)(1.0 + 0.1 + 1e-3);   // 1.101, matches reference
  const float HI  = (float)(1.0 - 1e-3);
  float px = p[3*n], py = p[3*n+1], pz = p[3*n+2];
  float nx = fminf(fmaxf(px / DEN + 0.5f, 0.0f), HI);
  float ny = fminf(fmaxf(py / DEN + 0.5f, 0.0f), HI);
  float nz = fminf(fmaxf(pz / DEN + 0.5f, 0.0f), HI);
  int ix = (int)(nx * 64.0f);
  int iy = (int)(ny * 64.0f);
  int iz = (int)(nz * 64.0f);
  int b = n / TPB;
  int i0 = ix + 64 * iz;   // plane (0,2) xz
  int i1 = ix + 64 * iy;   // plane (0,1) xy
  int i2 = iy + 64 * iz;   // plane (1,2) yz
  idx[0*NP + n] = i0;
  idx[1*NP + n] = i1;
  idx[2*NP + n] = i2;
  atomicAdd(&cnt[(0*NB + b)*SS + i0], 1u);
  atomicAdd(&cnt[(1*NB + b)*SS + i1], 1u);
  atomicAdd(&cnt[(2*NB + b)*SS + i2], 1u);
}

// ---------------- exclusive scan over 4096 bins per (plane,batch) ----------------
__global__ __launch_bounds__(256) void k_scan(const unsigned* __restrict__ cnt,
                                              int* __restrict__ off,
                                              int* __restrict__ cursor) {
  __shared__ unsigned sdata[SS];
  __shared__ unsigned ssum[256];
  __shared__ unsigned sbase[256];
  const int plb = blockIdx.x;
  const int tid = threadIdx.x;
  for (int j = tid; j < SS; j += 256) sdata[j] = cnt[(size_t)plb*SS + j];
  __syncthreads();
  unsigned local = 0;
  #pragma unroll
  for (int i = 0; i < 16; ++i) local += sdata[tid*16 + i];
  ssum[tid] = local;
  __syncthreads();
  if (tid == 0) {
    unsigned run = 0;
    for (int i = 0; i < 256; ++i) { sbase[i] = run; run += ssum[i]; }
  }
  __syncthreads();
  unsigned run = sbase[tid];
  #pragma unroll
  for (int i = 0; i < 16; ++i) {
    const int bin = tid*16 + i;
    off[plb*OFFP + bin] = (int)run;
    cursor[plb*OFFP + bin] = (int)run;
    run += sdata[bin];
  }
  if (tid == 255) off[plb*OFFP + SS] = (int)run;   // = 20000
}

// ---------------- counting-sort reorder (1 small atomic per point-plane) ----------------
__global__ __launch_bounds__(256) void k_reorder(const int* __restrict__ idx,
                                                 int* __restrict__ cursor,
                                                 int* __restrict__ order) {
  int n = blockIdx.x * 256 + threadIdx.x;
  if (n >= NP) return;
  int b = n / TPB;
  #pragma unroll
  for (int pl = 0; pl < 3; ++pl) {
    const int bin = idx[pl*NP + n];
    const int plb = pl*NB + b;
    const int pos = atomicAdd(&cursor[plb*OFFP + bin], 1);
    order[pl*NP + b*TPB + pos] = n;
  }
}

// ---------------- segmented scatter-max: fea[plb][bin][128] ----------------
__global__ __launch_bounds__(256) void k_pool(const float* __restrict__ net,
                                              const int* __restrict__ order,
                                              const int* __restrict__ off,
                                              float* __restrict__ fea) {
  const int plb = blockIdx.y;
  const int pl = plb >> 3, b = plb & 7;
  const int tid = threadIdx.x;
  const int g = tid >> 5, f4 = (tid & 31) << 2;
  const int bin = blockIdx.x * 8 + g;
  const int s = off[plb*OFFP + bin];
  const int e = off[plb*OFFP + bin + 1];
  const int base = pl*NP + b*TPB;
  const float NI = -__builtin_inff();
  float4 m0 = make_float4(NI,NI,NI,NI), m1 = m0, m2 = m0, m3 = m0;
  int t = s;
  for (; t + 3 < e; t += 4) {
    const int n0 = order[base+t],   n1 = order[base+t+1];
    const int n2 = order[base+t+2], n3 = order[base+t+3];
    const float4 v0 = *(const float4*)&net[(size_t)n0*H + f4];
    const float4 v1 = *(const float4*)&net[(size_t)n1*H + f4];
    const float4 v2 = *(const float4*)&net[(size_t)n2*H + f4];
    const float4 v3 = *(const float4*)&net[(size_t)n3*H + f4];
    m0 = max4(m0, v0); m1 = max4(m1, v1); m2 = max4(m2, v2); m3 = max4(m3, v3);
  }
  for (; t < e; ++t) {
    const int n0 = order[base+t];
    m0 = max4(m0, *(const float4*)&net[(size_t)n0*H + f4]);
  }
  float4 r = max4(max4(m0, m1), max4(m2, m3));
  if (s == e) r = make_float4(0.f, 0.f, 0.f, 0.f);
  *(float4*)&fea[((size_t)plb*SS + bin)*H + f4] = r;
}

// ---------------- fused ResnetBlockFC ----------------
// MODE 0: x = fc_pos(p) (256 wide), computed into LDS during staging.
// MODE 1: x = concat(net, sum_planes gather(fea)).
// Block: 64 points, 256 threads. Thread tile: 8 points x 4 features.
template<int MODE>
__global__ __launch_bounds__(256) void k_block(
    const float* __restrict__ p,
    const float* __restrict__ wpos, const float* __restrict__ bpos,
    float* __restrict__ net,
    const float* __restrict__ fea, const int* __restrict__ idx,
    const float* __restrict__ w0, const float* __restrict__ b0,
    const float* __restrict__ w1, const float* __restrict__ b1,
    const float* __restrict__ wsc)
{
  __shared__ float xa[64][H];   // x[0:128]
  __shared__ float xb[64][H];   // x[128:256]
  const int tid = threadIdx.x;
  const int n0 = blockIdx.x * 64;

  if (MODE == 0) {
    for (int j = tid; j < 64 * 64; j += 256) {
      const int pt = j >> 6;
      const int k4 = (j & 63) << 2;
      const int n = n0 + pt;
      const float px = p[3*n], py = p[3*n+1], pz = p[3*n+2];
      float4 a = *(const float4*)&bpos[k4];
      const float4 wx = *(const float4*)&wpos[k4];
      const float4 wy = *(const float4*)&wpos[256 + k4];
      const float4 wz = *(const float4*)&wpos[512 + k4];
      a.x += px*wx.x + py*wy.x + pz*wz.x;
      a.y += px*wx.y + py*wy.y + pz*wz.y;
      a.z += px*wx.z + py*wy.z + pz*wz.z;
      a.w += px*wx.w + py*wy.w + pz*wz.w;
      if (k4 < H) *(float4*)&xa[pt][k4] = a;
      else        *(float4*)&xb[pt][k4 - H] = a;
    }
  } else {
    for (int j = tid; j < 64 * 32; j += 256) {
      const int pt = j >> 5;
      const int k4 = (j & 31) << 2;
      const int n = n0 + pt;
      *(float4*)&xa[pt][k4] = *(const float4*)&net[(size_t)n*H + k4];
      const int b = n / TPB;
      float4 s = make_float4(0.f, 0.f, 0.f, 0.f);
      #pragma unroll
      for (int pl = 0; pl < 3; ++pl) {
        const int bin = idx[pl*NP + n];
        const float4 u = *(const float4*)&fea[(((size_t)(pl*NB + b))*SS + bin)*H + k4];
        s.x += u.x; s.y += u.y; s.z += u.z; s.w += u.w;
      }
      *(float4*)&xb[pt][k4] = s;
    }
  }
  __syncthreads();

  const int fg = tid & 31;
  const int pg = tid >> 5;
  const int f4 = fg << 2;
  const int prow = pg << 3;

  float a0[8][4];
  float as[8][4];
  #pragma unroll
  for (int i = 0; i < 8; ++i) {
    a0[i][0]=a0[i][1]=a0[i][2]=a0[i][3]=0.f;
    as[i][0]=as[i][1]=as[i][2]=as[i][3]=0.f;
  }

  // phase A part 1: k = 0..127 over xa (fc_0 on relu(x), shortcut on raw x)
  #pragma unroll 4
  for (int k = 0; k < H; ++k) {
    const float4 w0v = *(const float4*)&w0[(size_t)k*H + f4];
    const float4 wsv = *(const float4*)&wsc[(size_t)k*H + f4];
    #pragma unroll
    for (int i = 0; i < 8; ++i) {
      const float xv = xa[prow + i][k];
      const float r = fmaxf(xv, 0.f);
      a0[i][0] += r*w0v.x; a0[i][1] += r*w0v.y; a0[i][2] += r*w0v.z; a0[i][3] += r*w0v.w;
      as[i][0] += xv*wsv.x; as[i][1] += xv*wsv.y; as[i][2] += xv*wsv.z; as[i][3] += xv*wsv.w;
    }
  }
  // phase A part 2: k = 128..255 over xb
  #pragma unroll 4
  for (int k = 0; k < H; ++k) {
    const float4 w0v = *(const float4*)&w0[(size_t)(k + H)*H + f4];
    const float4 wsv = *(const float4*)&wsc[(size_t)(k + H)*H + f4];
    #pragma unroll
    for (int i = 0; i < 8; ++i) {
      const float xv = xb[prow + i][k];
      const float r = fmaxf(xv, 0.f);
      a0[i][0] += r*w0v.x; a0[i][1] += r*w0v.y; a0[i][2] += r*w0v.z; a0[i][3] += r*w0v.w;
      as[i][0] += xv*wsv.x; as[i][1] += xv*wsv.y; as[i][2] += xv*wsv.z; as[i][3] += xv*wsv.w;
    }
  }
  __syncthreads();

  // h = relu(fc0 + b0) -> reuse xa
  const float4 b0v = *(const float4*)&b0[f4];
  #pragma unroll
  for (int i = 0; i < 8; ++i) {
    float4 h;
    h.x = fmaxf(a0[i][0] + b0v.x, 0.f);
    h.y = fmaxf(a0[i][1] + b0v.y, 0.f);
    h.z = fmaxf(a0[i][2] + b0v.z, 0.f);
    h.w = fmaxf(a0[i][3] + b0v.w, 0.f);
    *(float4*)&xa[prow + i][f4] = h;
  }
  __syncthreads();

  // phase B: dx = h @ w1, accumulate into shortcut
  #pragma unroll 4
  for (int k = 0; k < H; ++k) {
    const float4 w1v = *(const float4*)&w1[(size_t)k*H + f4];
    #pragma unroll
    for (int i = 0; i < 8; ++i) {
      const float hv = xa[prow + i][k];
      as[i][0] += hv*w1v.x; as[i][1] += hv*w1v.y; as[i][2] += hv*w1v.z; as[i][3] += hv*w1v.w;
    }
  }

  const float4 b1v = *(const float4*)&b1[f4];
  #pragma unroll
  for (int i = 0; i < 8; ++i) {
    float4 o;
    o.x = as[i][0] + b1v.x;
    o.y = as[i][1] + b1v.y;
    o.z = as[i][2] + b1v.z;
    o.w = as[i][3] + b1v.w;
    *(float4*)&net[(size_t)(n0 + prow + i)*H + f4] = o;
  }
}

// ---------------- segmented mean + fc_c GEMM + transpose-out ----------------
// mean(net@W+b) == mean(net)@W + b  (affine commutes with mean)
__global__ __launch_bounds__(256) void k_meanout(const float* __restrict__ net,
                                                 const int* __restrict__ order,
                                                 const int* __restrict__ off,
                                                 const float* __restrict__ wc,
                                                 const float* __restrict__ bc,
                                                 float* __restrict__ out) {
  __shared__ float xa[64][132];   // 33.8 KB; pitch 132 keeps float4 writes 16B-aligned
  const int plb = blockIdx.y;
  const int pl = plb >> 3, b = plb & 7;
  const int s0 = blockIdx.x * 64;       // 64-bin tile
  const int tid = threadIdx.x;
  const int g = tid >> 5, f4 = (tid & 31) << 2;
  const int base = pl*NP + b*TPB;

  // phase 1: segmented mean of net rows for the 64 bins of this tile
  for (int q = 0; q < 8; ++q) {
    const int bi = g*8 + q;
    const int bin = s0 + bi;
    const int s = off[plb*OFFP + bin];
    const int e = off[plb*OFFP + bin + 1];
    float4 a0 = make_float4(0,0,0,0), a1 = a0, a2 = a0, a3 = a0;
    int t = s;
    for (; t + 3 < e; t += 4) {
      const int n0 = order[base+t],   n1 = order[base+t+1];
      const int n2 = order[base+t+2], n3 = order[base+t+3];
      const float4 v0 = *(const float4*)&net[(size_t)n0*H + f4];
      const float4 v1 = *(const float4*)&net[(size_t)n1*H + f4];
      const float4 v2 = *(const float4*)&net[(size_t)n2*H + f4];
      const float4 v3 = *(const float4*)&net[(size_t)n3*H + f4];
      a0.x+=v0.x; a0.y+=v0.y; a0.z+=v0.z; a0.w+=v0.w;
      a1.x+=v1.x; a1.y+=v1.y; a1.z+=v1.z; a1.w+=v1.w;
      a2.x+=v2.x; a2.y+=v2.y; a2.z+=v2.z; a2.w+=v2.w;
      a3.x+=v3.x; a3.y+=v3.y; a3.z+=v3.z; a3.w+=v3.w;
    }
    for (; t < e; ++t) {
      const int n0 = order[base+t];
      const float4 v0 = *(const float4*)&net[(size_t)n0*H + f4];
      a0.x+=v0.x; a0.y+=v0.y; a0.z+=v0.z; a0.w+=v0.w;
    }
    const float r = 1.0f / (float)((e - s) > 0 ? (e - s) : 1);
    float4 m;
    m.x = (a0.x+a1.x+a2.x+a3.x) * r;
    m.y = (a0.y+a1.y+a2.y+a3.y) * r;
    m.z = (a0.z+a1.z+a2.z+a3.z) * r;
    m.w = (a0.w+a1.w+a2.w+a3.w) * r;
    *(float4*)&xa[bi][f4] = m;
  }
  __syncthreads();

  // phase 2: [64 bins x 128] @ wc[128,128] + bc
  const int fg = tid & 31;
  const int pg = tid >> 5;
  const int f4c = fg << 2;
  const int prow = pg << 3;
  float ac[8][4];
  #pragma unroll
  for (int i = 0; i < 8; ++i) { ac[i][0]=ac[i][1]=ac[i][2]=ac[i][3]=0.f; }
  #pragma unroll 4
  for (int k = 0; k < H; ++k) {
    const float4 wv = *(const float4*)&wc[(size_t)k*H + f4c];
    #pragma unroll
    for (int i = 0; i < 8; ++i) {
      const float xv = xa[prow + i][k];
      ac[i][0] += xv*wv.x; ac[i][1] += xv*wv.y; ac[i][2] += xv*wv.z; ac[i][3] += xv*wv.w;
    }
  }
  __syncthreads();
  const float4 bv = *(const float4*)&bc[f4c];
  #pragma unroll
  for (int i = 0; i < 8; ++i) {
    float4 o;
    o.x = ac[i][0] + bv.x;
    o.y = ac[i][1] + bv.y;
    o.z = ac[i][2] + bv.z;
    o.w = ac[i][3] + bv.w;
    *(float4*)&xa[prow + i][f4c] = o;   // result back in [bin][ch] layout
  }
  __syncthreads();

  // phase 3: transpose-write out[plb][ch][s0..s0+63]
  for (int j = tid; j < H * 16; j += 256) {
    const int ch = j >> 4;
    const int s4 = (j & 15) << 2;
    float4 o;
    o.x = xa[s4 + 0][ch];
    o.y = xa[s4 + 1][ch];
    o.z = xa[s4 + 2][ch];
    o.w = xa[s4 + 3][ch];
    *(float4*)&out[((size_t)plb*H + ch)*SS + s0 + s4] = o;
  }
}

extern "C" void kernel_launch(void* const* d_in, const int* in_sizes, int n_in,
                              void* d_out, int out_size, void* d_ws, size_t ws_size,
                              hipStream_t stream) {
  (void)in_sizes; (void)n_in; (void)out_size; (void)ws_size;
  const float* p      = (const float*)d_in[0];
  const float* wpos   = (const float*)d_in[1];
  const float* bpos   = (const float*)d_in[2];
  const float* blk0w  = (const float*)d_in[3];
  const float* blk0b  = (const float*)d_in[4];
  const float* blk1w  = (const float*)d_in[5];
  const float* blk1b  = (const float*)d_in[6];
  const float* blkscw = (const float*)d_in[7];
  const float* wc     = (const float*)d_in[8];
  const float* bc     = (const float*)d_in[9];
  float* out = (float*)d_out;

  char* ws = (char*)d_ws;
  float* net    = (float*)ws;                        // NP*H*4      = 81,920,000
  int* idx      = (int*)(ws + 81920000);             // 3*NP*4      =  1,920,000
  int* order    = (int*)(ws + 83840000);             // 3*NP*4      =  1,920,000
  int* off      = (int*)(ws + 85760000);             // 24*4097*4   =    393,312
  int* cursor   = (int*)(ws + 86153312);             // 24*4097*4   =    393,312
  unsigned* cnt = (unsigned*)(ws + 86546624);        // 24*4096*4   =    393,216
                                                     // total        86,939,840 B
  float* fea = (float*)d_out;  // 3*NB*SS*H*4 = 50,331,648 B == out bytes exactly;
                               // fully rewritten by k_pool each round, finally
                               // overwritten by k_meanout.

  hipMemsetAsync(cnt, 0, (size_t)3 * NB * SS * 4, stream);
  k_idx<<<(NP + 255) / 256, 256, 0, stream>>>(p, idx, cnt);
  k_scan<<<24, 256, 0, stream>>>(cnt, off, cursor);
  k_reorder<<<(NP + 255) / 256, 256, 0, stream>>>(idx, cursor, order);

  // block 0: fc_pos fused
  k_block<0><<<NP / 64, 256, 0, stream>>>(p, wpos, bpos, net, nullptr, nullptr,
                                          blk0w, blk0b, blk1w, blk1b, blkscw);

  for (int i = 1; i < 5; ++i) {
    k_pool<<<dim3(SS / 8, 24), 256, 0, stream>>>(net, order, off, fea);
    k_block<1><<<NP / 64, 256, 0, stream>>>(nullptr, nullptr, nullptr, net, fea, idx,
                                            blk0w + (size_t)i * 256 * H,
                                            blk0b + (size_t)i * H,
                                            blk1w + (size_t)i * H * H,
                                            blk1b + (size_t)i * H,
                                            blkscw + (size_t)i * 256 * H);
  }

  k_meanout<<<dim3(64, 24), 256, 0, stream>>>(net, order, off, wc, bc, out);
}

// Round 3
// 1210.092 us; speedup vs baseline: 10.0553x; 3.1645x over previous
//
#include <hip/hip_runtime.h>
#include <cstdint>
#include <cstddef>

#define NP   160000   // total points (B*T)
#define NB   8        // batch
#define TPB  20000    // points per batch
#define H    128      // hidden dim
#define SS   4096     // bins per plane (64*64)

typedef _Float16 half8  __attribute__((ext_vector_type(8)));
typedef float    f32x16 __attribute__((ext_vector_type(16)));

// order-preserving float <-> u32 map (for atomicMax-based scatter-max)
__device__ __forceinline__ unsigned encf(float f) {
  unsigned u = __float_as_uint(f);
  return (u & 0x80000000u) ? ~u : (u | 0x80000000u);
}
__device__ __forceinline__ float decf(unsigned u) {
  unsigned b = (u & 0x80000000u) ? (u ^ 0x80000000u) : ~u;
  return __uint_as_float(b);
}
// packed relu on 4x f16 (2 u32): zero halves whose sign bit is set
__device__ __forceinline__ half8 reluh8(half8 x) {
  union { half8 h; unsigned u[4]; } a, o;
  a.h = x;
  #pragma unroll
  for (int i = 0; i < 4; ++i) {
    unsigned v = a.u[i];
    unsigned m = ((v >> 15) & 0x00010001u) * 0xFFFFu;  // 0xFFFF where sign set
    o.u[i] = v & ~m;
  }
  return o.h;
}

// ---------------- bin indices + counts ----------------
__global__ __launch_bounds__(256) void k_idx(const float* __restrict__ p,
                                             int* __restrict__ idx,
                                             unsigned* __restrict__ cnt) {
  int n = blockIdx.x * 256 + threadIdx.x;
  if (n >= NP) return;
  const float DEN = (float)(1.0 + 0.1 + 1e-3);
  const float HI  = (float)(1.0 - 1e-3);
  float px = p[3*n], py = p[3*n+1], pz = p[3*n+2];
  float nx = fminf(fmaxf(px / DEN + 0.5f, 0.0f), HI);
  float ny = fminf(fmaxf(py / DEN + 0.5f, 0.0f), HI);
  float nz = fminf(fmaxf(pz / DEN + 0.5f, 0.0f), HI);
  int ix = (int)(nx * 64.0f);
  int iy = (int)(ny * 64.0f);
  int iz = (int)(nz * 64.0f);
  int b = n / TPB;
  int i0 = ix + 64 * iz;
  int i1 = ix + 64 * iy;
  int i2 = iy + 64 * iz;
  idx[0*NP + n] = i0;
  idx[1*NP + n] = i1;
  idx[2*NP + n] = i2;
  atomicAdd(&cnt[(0*NB + b)*SS + i0], 1u);
  atomicAdd(&cnt[(1*NB + b)*SS + i1], 1u);
  atomicAdd(&cnt[(2*NB + b)*SS + i2], 1u);
}

// ---------------- exclusive scan -> cursor ----------------
__global__ __launch_bounds__(256) void k_scan(const unsigned* __restrict__ cnt,
                                              int* __restrict__ cursor) {
  __shared__ unsigned sdata[SS];
  __shared__ unsigned ssum[256];
  __shared__ unsigned sbase[256];
  const int plb = blockIdx.x;
  const int tid = threadIdx.x;
  for (int j = tid; j < SS; j += 256) sdata[j] = cnt[(size_t)plb*SS + j];
  __syncthreads();
  unsigned local = 0;
  #pragma unroll
  for (int i = 0; i < 16; ++i) local += sdata[tid*16 + i];
  ssum[tid] = local;
  __syncthreads();
  if (tid == 0) {
    unsigned run = 0;
    for (int i = 0; i < 256; ++i) { sbase[i] = run; run += ssum[i]; }
  }
  __syncthreads();
  unsigned run = sbase[tid];
  #pragma unroll
  for (int i = 0; i < 16; ++i) {
    const int bin = tid*16 + i;
    cursor[plb*SS + bin] = (int)run;
    run += sdata[bin];
  }
}

// ---------------- counting-sort reorder; pack (bin<<18)|n ----------------
__global__ __launch_bounds__(256) void k_reorder(const int* __restrict__ idx,
                                                 int* __restrict__ cursor,
                                                 int* __restrict__ order) {
  int n = blockIdx.x * 256 + threadIdx.x;
  if (n >= NP) return;
  int b = n / TPB;
  #pragma unroll
  for (int pl = 0; pl < 3; ++pl) {
    const int bin = idx[pl*NP + n];
    const int plb = pl*NB + b;
    const int pos = atomicAdd(&cursor[plb*SS + bin], 1);
    order[pl*NP + b*TPB + pos] = (bin << 18) | n;
  }
}

// ---------------- weights fp32 -> f16 in MFMA B-fragment order ----------------
// per layer (81920 f16): [W0 16kt x 4nt x 64lane x 8 | Wsc same | W1 8kt x 4nt x 64 x 8]
// frag elem j of lane l, tile (kt,nt):  W[kt*16 + 8*(l>>5)+j][nt*32 + (l&31)]
__global__ __launch_bounds__(256) void k_wconv(const float* __restrict__ w0,
                                               const float* __restrict__ w1,
                                               const float* __restrict__ wsc,
                                               _Float16* __restrict__ wb) {
  int t = blockIdx.x*256 + threadIdx.x;
  if (t >= 51200) return;
  int L = t / 10240, r = t % 10240;
  const float* src; _Float16* dst; int q;
  if (r < 4096)      { q = r;        src = w0  + L*32768; dst = wb + L*81920;         }
  else if (r < 8192) { q = r - 4096; src = wsc + L*32768; dst = wb + L*81920 + 32768; }
  else               { q = r - 8192; src = w1  + L*16384; dst = wb + L*81920 + 65536; }
  int kt = q >> 8, nt = (q >> 6) & 3, l = q & 63;
  int k0 = kt*16 + ((l >> 5) << 3);
  int n  = nt*32 + (l & 31);
  union { _Float16 h[8]; uint4 u; } o;
  #pragma unroll
  for (int j = 0; j < 8; ++j) o.h[j] = (_Float16)src[(size_t)(k0 + j)*H + n];
  *(uint4*)(dst + (size_t)q*8) = o.u;
}

// ---------------- chunked scatter-max (balanced, tagged atomicMax) ----------------
__global__ __launch_bounds__(256) void k_pool(const _Float16* __restrict__ net,
                                              const int* __restrict__ order,
                                              unsigned* __restrict__ ubuf, int round) {
  const int tid = threadIdx.x;
  const int cid = blockIdx.x*8 + (tid >> 5);
  if (cid >= 625) return;
  const int gi  = tid & 31;
  const int plb = blockIdx.y;
  const int pl  = plb >> 3, b = plb & 7;
  const int pk0 = order[pl*NP + b*TPB + cid*32 + gi];
  const int f4  = gi << 2;
  const unsigned tag = ((unsigned)round) << 29;
  int cur = __shfl(pk0, 0, 32) >> 18;
  float m0 = -3.0e38f, m1 = m0, m2 = m0, m3 = m0;
  #pragma unroll 4
  for (int i = 0; i < 32; ++i) {
    int pk  = __shfl(pk0, i, 32);
    int bin = pk >> 18;
    if (bin != cur) {
      unsigned* u = &ubuf[((size_t)plb*SS + cur)*H + f4];
      atomicMax(u+0, tag | (encf(m0) >> 3));
      atomicMax(u+1, tag | (encf(m1) >> 3));
      atomicMax(u+2, tag | (encf(m2) >> 3));
      atomicMax(u+3, tag | (encf(m3) >> 3));
      cur = bin; m0 = m1 = m2 = m3 = -3.0e38f;
    }
    int n = pk & 0x3FFFF;
    union { uint2 u; _Float16 h[4]; } v;
    v.u = *(const uint2*)&net[(size_t)n*H + f4];
    m0 = fmaxf(m0, (float)v.h[0]);
    m1 = fmaxf(m1, (float)v.h[1]);
    m2 = fmaxf(m2, (float)v.h[2]);
    m3 = fmaxf(m3, (float)v.h[3]);
  }
  unsigned* u = &ubuf[((size_t)plb*SS + cur)*H + f4];
  atomicMax(u+0, tag | (encf(m0) >> 3));
  atomicMax(u+1, tag | (encf(m1) >> 3));
  atomicMax(u+2, tag | (encf(m2) >> 3));
  atomicMax(u+3, tag | (encf(m3) >> 3));
}

// ---------------- chunked scatter-sum (for final mean) ----------------
__global__ __launch_bounds__(256) void k_sum(const _Float16* __restrict__ net,
                                             const int* __restrict__ order,
                                             float* __restrict__ sums) {
  const int tid = threadIdx.x;
  const int cid = blockIdx.x*8 + (tid >> 5);
  if (cid >= 625) return;
  const int gi  = tid & 31;
  const int plb = blockIdx.y;
  const int pl  = plb >> 3, b = plb & 7;
  const int pk0 = order[pl*NP + b*TPB + cid*32 + gi];
  const int f4  = gi << 2;
  int cur = __shfl(pk0, 0, 32) >> 18;
  float s0 = 0.f, s1 = 0.f, s2 = 0.f, s3 = 0.f;
  #pragma unroll 4
  for (int i = 0; i < 32; ++i) {
    int pk  = __shfl(pk0, i, 32);
    int bin = pk >> 18;
    if (bin != cur) {
      float* u = &sums[((size_t)plb*SS + cur)*H + f4];
      atomicAdd(u+0, s0); atomicAdd(u+1, s1);
      atomicAdd(u+2, s2); atomicAdd(u+3, s3);
      cur = bin; s0 = s1 = s2 = s3 = 0.f;
    }
    int n = pk & 0x3FFFF;
    union { uint2 u; _Float16 h[4]; } v;
    v.u = *(const uint2*)&net[(size_t)n*H + f4];
    s0 += (float)v.h[0]; s1 += (float)v.h[1];
    s2 += (float)v.h[2]; s3 += (float)v.h[3];
  }
  float* u = &sums[((size_t)plb*SS + cur)*H + f4];
  atomicAdd(u+0, s0); atomicAdd(u+1, s1);
  atomicAdd(u+2, s2); atomicAdd(u+3, s3);
}

// ---------------- fused ResnetBlockFC via mfma_f32_32x32x16_f16 ----------------
// 64-pt tile, 256 thr = 4 waves; wave w: all 64 rows x cols [w*32, w*32+32)
// LDS: Xs [64][256] f16 (XOR-swizzled), Hs [64][128] f16 (XOR-swizzled) = 48 KB
template<int MODE>
__global__ __launch_bounds__(256, 3) void k_block(
    const float* __restrict__ p,
    const float* __restrict__ wpos, const float* __restrict__ bpos,
    _Float16* __restrict__ net,
    const unsigned* __restrict__ ubuf, const int* __restrict__ idx,
    const _Float16* __restrict__ wb,
    const float* __restrict__ b0, const float* __restrict__ b1, int round)
{
  __shared__ char smem[49152];
  char* Xs = smem;            // 32768 B: x[64][256] f16, byte ^= ((row&7)<<4)
  char* Hs = smem + 32768;    // 16384 B: h[64][128] f16, byte ^= ((row&7)<<4)
  const int tid = threadIdx.x;
  const int n0  = blockIdx.x * 64;

  if (MODE == 0) {
    for (int j = tid; j < 64*64; j += 256) {
      int pt = j >> 6, k4 = (j & 63) << 2;
      int n = n0 + pt;
      float px = p[3*n], py = p[3*n+1], pz = p[3*n+2];
      float4 a  = *(const float4*)&bpos[k4];
      float4 wx = *(const float4*)&wpos[k4];
      float4 wy = *(const float4*)&wpos[256 + k4];
      float4 wz = *(const float4*)&wpos[512 + k4];
      a.x += px*wx.x + py*wy.x + pz*wz.x;
      a.y += px*wx.y + py*wy.y + pz*wz.y;
      a.z += px*wx.z + py*wy.z + pz*wz.z;
      a.w += px*wx.w + py*wy.w + pz*wz.w;
      union { _Float16 h[4]; uint2 u; } o;
      o.h[0] = (_Float16)a.x; o.h[1] = (_Float16)a.y;
      o.h[2] = (_Float16)a.z; o.h[3] = (_Float16)a.w;
      *(uint2*)(Xs + ((pt*512 + k4*2) ^ ((pt & 7) << 4))) = o.u;
    }
  } else {
    for (int j = tid; j < 64*32; j += 256) {       // first half: copy net row (f16)
      int pt = j >> 5, k4 = (j & 31) << 2;
      int n = n0 + pt;
      uint2 v = *(const uint2*)&net[(size_t)n*H + k4];
      *(uint2*)(Xs + ((pt*512 + k4*2) ^ ((pt & 7) << 4))) = v;
    }
    const unsigned rtag = ((unsigned)round) << 29;
    for (int j = tid; j < 64*32; j += 256) {       // second half: pooled gather
      int pt = j >> 5, f4 = (j & 31) << 2;
      int n = n0 + pt;
      int b = n / TPB;
      float s0 = 0.f, s1 = 0.f, s2 = 0.f, s3 = 0.f;
      #pragma unroll
      for (int pl = 0; pl < 3; ++pl) {
        int bin = idx[pl*NP + n];
        const uint4 u = *(const uint4*)&ubuf[(((size_t)(pl*NB + b))*SS + bin)*H + f4];
        s0 += ((u.x >> 29) == (rtag >> 29)) ? decf((u.x & 0x1FFFFFFFu) << 3) : 0.f;
        s1 += ((u.y >> 29) == (rtag >> 29)) ? decf((u.y & 0x1FFFFFFFu) << 3) : 0.f;
        s2 += ((u.z >> 29) == (rtag >> 29)) ? decf((u.z & 0x1FFFFFFFu) << 3) : 0.f;
        s3 += ((u.w >> 29) == (rtag >> 29)) ? decf((u.w & 0x1FFFFFFFu) << 3) : 0.f;
      }
      union { _Float16 h[4]; uint2 u; } o;
      o.h[0] = (_Float16)s0; o.h[1] = (_Float16)s1;
      o.h[2] = (_Float16)s2; o.h[3] = (_Float16)s3;
      *(uint2*)(Xs + ((pt*512 + 256 + f4*2) ^ ((pt & 7) << 4))) = o.u;
    }
  }
  __syncthreads();

  const int w  = tid >> 6;          // wave id = n-tile
  const int ln = tid & 63;
  const int l5 = ln >> 5;
  const int lr = ln & 31;
  const int sw = (lr & 7) << 4;     // (row&7)<<4 — same for row lr and 32+lr
  const int a0b = lr*512 + l5*16;
  const int a1b = a0b + 32*512;

  f32x16 aR0 = {}, aR1 = {}, aS0 = {}, aS1 = {};
  const _Float16* wb0 = wb;
  const _Float16* wbs = wb + 32768;

  #pragma unroll 4
  for (int kt = 0; kt < 16; ++kt) {
    half8 x0 = *(const half8*)(Xs + ((a0b + kt*32) ^ sw));
    half8 x1 = *(const half8*)(Xs + ((a1b + kt*32) ^ sw));
    half8 r0 = reluh8(x0);
    half8 r1 = reluh8(x1);
    half8 bw = *(const half8*)(wb0 + ((kt*4 + w)*64 + ln)*8);
    half8 bs = *(const half8*)(wbs + ((kt*4 + w)*64 + ln)*8);
    aR0 = __builtin_amdgcn_mfma_f32_32x32x16_f16(r0, bw, aR0, 0, 0, 0);
    aR1 = __builtin_amdgcn_mfma_f32_32x32x16_f16(r1, bw, aR1, 0, 0, 0);
    aS0 = __builtin_amdgcn_mfma_f32_32x32x16_f16(x0, bs, aS0, 0, 0, 0);
    aS1 = __builtin_amdgcn_mfma_f32_32x32x16_f16(x1, bs, aS1, 0, 0, 0);
  }

  // h = relu(fc0 + b0) -> Hs   (C/D: col = lane&31, row = (reg&3)+8*(reg>>2)+4*(lane>>5))
  const int col = w*32 + lr;
  const float bb0 = b0[col];
  #pragma unroll
  for (int reg = 0; reg < 16; ++reg) {
    int ro = (reg & 3) + 8*(reg >> 2) + 4*l5;
    float v0 = fmaxf(aR0[reg] + bb0, 0.f);
    float v1 = fmaxf(aR1[reg] + bb0, 0.f);
    *(_Float16*)(Hs + ((ro*256 + col*2) ^ ((ro & 7) << 4)))        = (_Float16)v0;
    *(_Float16*)(Hs + (((32+ro)*256 + col*2) ^ ((ro & 7) << 4)))   = (_Float16)v1;
  }
  __syncthreads();

  const _Float16* wb1 = wb + 65536;
  #pragma unroll 2
  for (int kt = 0; kt < 8; ++kt) {
    half8 h0 = *(const half8*)(Hs + ((lr*256 + l5*16 + kt*32) ^ sw));
    half8 h1 = *(const half8*)(Hs + (((32+lr)*256 + l5*16 + kt*32) ^ sw));
    half8 bf = *(const half8*)(wb1 + ((kt*4 + w)*64 + ln)*8);
    aS0 = __builtin_amdgcn_mfma_f32_32x32x16_f16(h0, bf, aS0, 0, 0, 0);
    aS1 = __builtin_amdgcn_mfma_f32_32x32x16_f16(h1, bf, aS1, 0, 0, 0);
  }

  const float bb1 = b1[col];
  #pragma unroll
  for (int reg = 0; reg < 16; ++reg) {
    int ro = (reg & 3) + 8*(reg >> 2) + 4*l5;
    net[(size_t)(n0 + ro)*H + col]      = (_Float16)(aS0[reg] + bb1);
    net[(size_t)(n0 + 32 + ro)*H + col] = (_Float16)(aS1[reg] + bb1);
  }
}

// ---------------- mean-normalize + fc_c GEMM + transpose-out ----------------
__global__ __launch_bounds__(256) void k_out2(const float* __restrict__ sums,
                                              const unsigned* __restrict__ cnt,
                                              const float* __restrict__ wc,
                                              const float* __restrict__ bc,
                                              float* __restrict__ out) {
  __shared__ float xa[64][132];
  const int plb = blockIdx.y;
  const int s0  = blockIdx.x << 6;
  const int tid = threadIdx.x;

  for (int j = tid; j < 64*32; j += 256) {
    int si = j >> 5, k4 = (j & 31) << 2;
    int s = s0 + si;
    float4 v = *(const float4*)&sums[((size_t)plb*SS + s)*H + k4];
    unsigned c = cnt[(size_t)plb*SS + s];
    float r = 1.0f / (float)(c > 0u ? c : 1u);
    xa[si][k4+0] = v.x*r; xa[si][k4+1] = v.y*r;
    xa[si][k4+2] = v.z*r; xa[si][k4+3] = v.w*r;
  }
  __syncthreads();

  const int fg = tid & 31;
  const int pg = tid >> 5;
  const int f4c = fg << 2;
  const int prow = pg << 3;
  float ac[8][4];
  #pragma unroll
  for (int i = 0; i < 8; ++i) { ac[i][0]=ac[i][1]=ac[i][2]=ac[i][3]=0.f; }
  #pragma unroll 4
  for (int k = 0; k < H; ++k) {
    const float4 wv = *(const float4*)&wc[(size_t)k*H + f4c];
    #pragma unroll
    for (int i = 0; i < 8; ++i) {
      const float xv = xa[prow + i][k];
      ac[i][0] += xv*wv.x; ac[i][1] += xv*wv.y; ac[i][2] += xv*wv.z; ac[i][3] += xv*wv.w;
    }
  }
  __syncthreads();
  const float4 bv = *(const float4*)&bc[f4c];
  #pragma unroll
  for (int i = 0; i < 8; ++i) {
    float4 o;
    o.x = ac[i][0] + bv.x;
    o.y = ac[i][1] + bv.y;
    o.z = ac[i][2] + bv.z;
    o.w = ac[i][3] + bv.w;
    *(float4*)&xa[prow + i][f4c] = o;
  }
  __syncthreads();

  for (int j = tid; j < H * 16; j += 256) {
    const int ch = j >> 4;
    const int s4 = (j & 15) << 2;
    float4 o;
    o.x = xa[s4 + 0][ch];
    o.y = xa[s4 + 1][ch];
    o.z = xa[s4 + 2][ch];
    o.w = xa[s4 + 3][ch];
    *(float4*)&out[((size_t)plb*H + ch)*SS + s0 + s4] = o;
  }
}

extern "C" void kernel_launch(void* const* d_in, const int* in_sizes, int n_in,
                              void* d_out, int out_size, void* d_ws, size_t ws_size,
                              hipStream_t stream) {
  (void)in_sizes; (void)n_in; (void)out_size; (void)ws_size;
  const float* p      = (const float*)d_in[0];
  const float* wpos   = (const float*)d_in[1];
  const float* bpos   = (const float*)d_in[2];
  const float* blk0w  = (const float*)d_in[3];
  const float* blk0b  = (const float*)d_in[4];
  const float* blk1w  = (const float*)d_in[5];
  const float* blk1b  = (const float*)d_in[6];
  const float* blkscw = (const float*)d_in[7];
  const float* wc     = (const float*)d_in[8];
  const float* bc     = (const float*)d_in[9];
  float* out = (float*)d_out;

  char* ws = (char*)d_ws;
  _Float16* net  = (_Float16*)ws;                    // NP*H*2      = 40,960,000
  int* idx       = (int*)(ws + 40960000);            // 3*NP*4      =  1,920,000
  int* order     = (int*)(ws + 42880000);            // 3*NP*4      =  1,920,000
  int* cursor    = (int*)(ws + 44800000);            // 24*SS*4     =    393,216
  unsigned* cnt  = (unsigned*)(ws + 45193216);       // 24*SS*4     =    393,216
  _Float16* wb   = (_Float16*)(ws + 45586432);       // 5*81920*2   =    819,200
  float* sums    = (float*)(ws + 46405632);          // 24*SS*H*4   = 50,331,648
                                                     // total       = 96,737,280 B
  unsigned* ubuf = (unsigned*)d_out;                 // 50,331,648 B == out bytes

  hipMemsetAsync(cnt, 0, 393216, stream);
  hipMemsetAsync(d_out, 0, 50331648, stream);        // ubuf init (tag 0 loses to all)

  k_idx<<<625, 256, 0, stream>>>(p, idx, cnt);
  k_scan<<<24, 256, 0, stream>>>(cnt, cursor);
  k_reorder<<<625, 256, 0, stream>>>(idx, cursor, order);
  k_wconv<<<200, 256, 0, stream>>>(blk0w, blk1w, blkscw, wb);

  k_block<0><<<2500, 256, 0, stream>>>(p, wpos, bpos, net, nullptr, idx,
                                       wb, blk0b, blk1b, 0);

  for (int i = 1; i < 5; ++i) {
    k_pool<<<dim3(79, 24), 256, 0, stream>>>(net, order, ubuf, i);
    k_block<1><<<2500, 256, 0, stream>>>(nullptr, nullptr, nullptr, net, ubuf, idx,
                                         wb + (size_t)i*81920,
                                         blk0b + (size_t)i*H,
                                         blk1b + (size_t)i*H, i);
  }

  hipMemsetAsync(sums, 0, 50331648, stream);
  k_sum<<<dim3(79, 24), 256, 0, stream>>>(net, order, sums);
  k_out2<<<dim3(64, 24), 256, 0, stream>>>(sums, cnt, wc, bc, out);
}